// Round 1
// baseline (336.274 us; speedup 1.0000x reference)
//
#include <hip/hip_runtime.h>

// MultiHeadedAttention: B=4, S=2048, H=16, D_K=64, D_MODEL=1024
// Pipeline: [gemm_qkv z=0..2] -> [flash attn] -> [gemm_out]
// ws layout (needs 64MB):
//   q_ws [64][2048][64] bf16 @ 0        (16 MB)  (pre-scaled by 0.125)
//   k_ws [64][2048][64] bf16 @ 16MB     (16 MB)
//   v_ws [64][2048][64] bf16 @ 32MB     (16 MB)
//   o_ws [4][2048][1024] bf16 @ 48MB    (16 MB)

#define DMODEL 1024
#define SLEN 2048
#define NHEAD 16

typedef __attribute__((ext_vector_type(4))) float f32x4;
typedef __attribute__((ext_vector_type(8))) short bf16x8;
typedef __attribute__((ext_vector_type(4))) int i32x4;
typedef __attribute__((ext_vector_type(2))) int i32x2;

__device__ __forceinline__ unsigned short f2bf(float f) {
  union { float f; unsigned u; } v; v.f = f;
  unsigned u = v.u;
  u += 0x7FFFu + ((u >> 16) & 1u);   // RNE
  return (unsigned short)(u >> 16);
}
__device__ __forceinline__ unsigned pack2(float a, float b) {
  return (unsigned)f2bf(a) | ((unsigned)f2bf(b) << 16);
}
__device__ __forceinline__ f32x4 zero4() {
  f32x4 z; z[0] = 0.f; z[1] = 0.f; z[2] = 0.f; z[3] = 0.f; return z;
}

// ---------------------------------------------------------------------------
// QKV projection: Y = X @ W^T + b ; M=8192,N=1024,K=1024 ; out bf16 per-head
// LDS rows padded to 40 elems (80B): frag ds_read_b128 lands 2-way on banks.
// ---------------------------------------------------------------------------
__global__ __launch_bounds__(256)
void gemm_qkv(const float* __restrict__ xq, const float* __restrict__ xk,
              const float* __restrict__ xv,
              const float* __restrict__ Wq, const float* __restrict__ bq,
              const float* __restrict__ Wk, const float* __restrict__ bk,
              const float* __restrict__ Wv, const float* __restrict__ bv,
              unsigned short* __restrict__ qw, unsigned short* __restrict__ kw,
              unsigned short* __restrict__ vw)
{
  const int z = blockIdx.z;
  const float* __restrict__ X    = (z == 0) ? xq : (z == 1) ? xk : xv;
  const float* __restrict__ W    = (z == 0) ? Wq : (z == 1) ? Wk : Wv;
  const float* __restrict__ bias = (z == 0) ? bq : (z == 1) ? bk : bv;
  unsigned short* __restrict__ dst = (z == 0) ? qw : (z == 1) ? kw : vw;
  const float scale = (z == 0) ? 0.125f : 1.0f;   // fold 1/sqrt(D_K) into Q

  const int n0 = blockIdx.x * 128;
  const int m0 = blockIdx.y * 128;
  const int tid = threadIdx.x;
  const int lane = tid & 63, wid = tid >> 6;
  const int l15 = lane & 15, g = lane >> 4;
  const int wr = wid >> 1, wc = wid & 1;

  __shared__ __align__(16) unsigned short Al[128 * 40];
  __shared__ __align__(16) unsigned short Bl[128 * 40];

  const int srow = tid >> 1, sh = tid & 1;   // 2 threads/row, 16 floats each
  const float* __restrict__ Ag = X + (size_t)(m0 + srow) * DMODEL + sh * 16;
  const float* __restrict__ Bg = W + (size_t)(n0 + srow) * DMODEL + sh * 16;

  f32x4 acc[4][4];
#pragma unroll
  for (int i = 0; i < 4; ++i)
#pragma unroll
    for (int j = 0; j < 4; ++j) acc[i][j] = zero4();

  f32x4 ar[4], br[4];
#pragma unroll
  for (int i = 0; i < 4; ++i) {
    ar[i] = *(const f32x4*)(Ag + i * 4);
    br[i] = *(const f32x4*)(Bg + i * 4);
  }

  for (int kk = 0; kk < 32; ++kk) {
    __syncthreads();
    i32x4 wa0, wa1, wb0, wb1;
    wa0[0] = pack2(ar[0][0], ar[0][1]); wa0[1] = pack2(ar[0][2], ar[0][3]);
    wa0[2] = pack2(ar[1][0], ar[1][1]); wa0[3] = pack2(ar[1][2], ar[1][3]);
    wa1[0] = pack2(ar[2][0], ar[2][1]); wa1[1] = pack2(ar[2][2], ar[2][3]);
    wa1[2] = pack2(ar[3][0], ar[3][1]); wa1[3] = pack2(ar[3][2], ar[3][3]);
    wb0[0] = pack2(br[0][0], br[0][1]); wb0[1] = pack2(br[0][2], br[0][3]);
    wb0[2] = pack2(br[1][0], br[1][1]); wb0[3] = pack2(br[1][2], br[1][3]);
    wb1[0] = pack2(br[2][0], br[2][1]); wb1[1] = pack2(br[2][2], br[2][3]);
    wb1[2] = pack2(br[3][0], br[3][1]); wb1[3] = pack2(br[3][2], br[3][3]);
    *(i32x4*)&Al[srow * 40 + sh * 16]     = wa0;
    *(i32x4*)&Al[srow * 40 + sh * 16 + 8] = wa1;
    *(i32x4*)&Bl[srow * 40 + sh * 16]     = wb0;
    *(i32x4*)&Bl[srow * 40 + sh * 16 + 8] = wb1;
    __syncthreads();
    if (kk < 31) {
      const float* Ap = Ag + (kk + 1) * 32;
      const float* Bp = Bg + (kk + 1) * 32;
#pragma unroll
      for (int i = 0; i < 4; ++i) {
        ar[i] = *(const f32x4*)(Ap + i * 4);
        br[i] = *(const f32x4*)(Bp + i * 4);
      }
    }
    bf16x8 afr[4], bfr[4];
#pragma unroll
    for (int i = 0; i < 4; ++i) {
      afr[i] = *(const bf16x8*)&Al[(wr * 64 + i * 16 + l15) * 40 + g * 8];
      bfr[i] = *(const bf16x8*)&Bl[(wc * 64 + i * 16 + l15) * 40 + g * 8];
    }
#pragma unroll
    for (int mi = 0; mi < 4; ++mi)
#pragma unroll
      for (int ni = 0; ni < 4; ++ni)
        acc[mi][ni] = __builtin_amdgcn_mfma_f32_16x16x32_bf16(
            afr[mi], bfr[ni], acc[mi][ni], 0, 0, 0);
  }

  // epilogue: bias, scale, scatter to [b*H+h][s][d] bf16
  float bv4[4];
#pragma unroll
  for (int ni = 0; ni < 4; ++ni) bv4[ni] = bias[n0 + wc * 64 + ni * 16 + l15];
#pragma unroll
  for (int mi = 0; mi < 4; ++mi) {
#pragma unroll
    for (int ni = 0; ni < 4; ++ni) {
      const int n = n0 + wc * 64 + ni * 16 + l15;
      const int h = n >> 6, d = n & 63;
#pragma unroll
      for (int r = 0; r < 4; ++r) {
        const int m = m0 + wr * 64 + mi * 16 + 4 * g + r;
        const int b = m >> 11, s = m & 2047;
        const float val = (acc[mi][ni][r] + bv4[ni]) * scale;
        dst[((size_t)(b * NHEAD + h) * SLEN + s) * 64 + d] = f2bf(val);
      }
    }
  }
}

// ---------------------------------------------------------------------------
// Flash attention. Block = 4 waves x 16 q-rows (QBLK 64). KVBLK = 64.
// Swapped QK^T: sac = mfma(K_frag, Q_frag) -> lane owns q = lane&15.
// ---------------------------------------------------------------------------
__global__ __launch_bounds__(256)
void attn(const unsigned short* __restrict__ q_ws,
          const unsigned short* __restrict__ k_ws,
          const unsigned short* __restrict__ v_ws,
          const int* __restrict__ mask,
          unsigned short* __restrict__ o_ws)
{
  const int bh = blockIdx.x;            // 0..63
  const int qt = blockIdx.y;            // 0..31
  const int b = bh >> 4, h = bh & 15;
  const int tid = threadIdx.x, w = tid >> 6, lane = tid & 63;
  const int l15 = lane & 15, g = lane >> 4;

  __shared__ __align__(16) unsigned short Kl[64 * 72];      // [kv][d] +8 pad
  __shared__ __align__(16) unsigned short Vt[64 * 72];      // [d][kv] +8 pad
  __shared__ __align__(16) unsigned short Pl[4][16 * 72];   // per-wave [q][kv]
  __shared__ __align__(16) float mkf[64];

  const size_t head_base = (size_t)bh * SLEN;
  const int qrow = qt * 64 + w * 16 + l15;
  const unsigned short* qb = q_ws + (head_base + qrow) * 64;
  const bf16x8 qf0 = *(const bf16x8*)(qb + g * 8);        // d 0..31 slice
  const bf16x8 qf1 = *(const bf16x8*)(qb + 32 + g * 8);   // d 32..63 slice

  float m_run = -1e30f, l_part = 0.f;
  f32x4 of[4];
#pragma unroll
  for (int n = 0; n < 4; ++n) of[n] = zero4();

  const int krow = tid >> 2, kq = tid & 3;     // K staging: 4 thr/row, 32B ea
  const int vkv = tid & 63, vdg = tid >> 6;    // V staging: kv=lane -> no LDS bank conflict

  for (int kt = 0; kt < 32; ++kt) {
    const int kv0 = kt * 64;
    // ---- stage K tile [64][64] (linear, padded rows) ----
    const unsigned short* ks = k_ws + (head_base + kv0 + krow) * 64 + kq * 16;
    const i32x4 k16a = *(const i32x4*)ks;
    const i32x4 k16b = *(const i32x4*)(ks + 8);
    // ---- stage V transposed: Vt[d][kv] ----
    const unsigned short* vs = v_ws + (head_base + kv0 + vkv) * 64 + vdg * 8;
    const i32x4 v16a = *(const i32x4*)vs;         // d = vdg*8 .. +7
    const i32x4 v16b = *(const i32x4*)(vs + 32);  // d = vdg*8+32 .. +7
    *(i32x4*)&Kl[krow * 72 + kq * 16]     = k16a;
    *(i32x4*)&Kl[krow * 72 + kq * 16 + 8] = k16b;
#pragma unroll
    for (int j = 0; j < 4; ++j) {
      const unsigned w0 = (unsigned)v16a[j];
      Vt[(vdg * 8 + 2 * j) * 72 + vkv]     = (unsigned short)(w0 & 0xFFFFu);
      Vt[(vdg * 8 + 2 * j + 1) * 72 + vkv] = (unsigned short)(w0 >> 16);
      const unsigned w1 = (unsigned)v16b[j];
      Vt[(vdg * 8 + 32 + 2 * j) * 72 + vkv]     = (unsigned short)(w1 & 0xFFFFu);
      Vt[(vdg * 8 + 32 + 2 * j + 1) * 72 + vkv] = (unsigned short)(w1 >> 16);
    }
    if (tid < 64) mkf[tid] = (mask[b * SLEN + kv0 + tid] == 0) ? -1e9f : 0.f;
    __syncthreads();

    // ---- S^T = K @ Q^T : sac[s][r] = score(q=l15, kv=16s+4g+r) ----
    f32x4 sac[4];
#pragma unroll
    for (int s = 0; s < 4; ++s) {
      const bf16x8 kf0 = *(const bf16x8*)&Kl[(s * 16 + l15) * 72 + g * 8];
      const bf16x8 kf1 = *(const bf16x8*)&Kl[(s * 16 + l15) * 72 + 32 + g * 8];
      f32x4 zt = zero4();
      zt = __builtin_amdgcn_mfma_f32_16x16x32_bf16(kf0, qf0, zt, 0, 0, 0);
      sac[s] = __builtin_amdgcn_mfma_f32_16x16x32_bf16(kf1, qf1, zt, 0, 0, 0);
    }

    // ---- mask + online softmax (stats owned per q = l15) ----
    float sv[4][4];
    float tmax = -1e30f;
#pragma unroll
    for (int s = 0; s < 4; ++s) {
      const f32x4 mv = *(const f32x4*)&mkf[s * 16 + g * 4];
#pragma unroll
      for (int r = 0; r < 4; ++r) {
        sv[s][r] = sac[s][r] + mv[r];
        tmax = fmaxf(tmax, sv[s][r]);
      }
    }
    tmax = fmaxf(tmax, __shfl_xor(tmax, 16));
    tmax = fmaxf(tmax, __shfl_xor(tmax, 32));
    const float m_new = fmaxf(m_run, tmax);
    const float alpha = __expf(m_run - m_new);
    float psum = 0.f;
#pragma unroll
    for (int s = 0; s < 4; ++s) {
      const float p0 = __expf(sv[s][0] - m_new);
      const float p1 = __expf(sv[s][1] - m_new);
      const float p2 = __expf(sv[s][2] - m_new);
      const float p3 = __expf(sv[s][3] - m_new);
      psum += (p0 + p1) + (p2 + p3);
      i32x2 pw; pw[0] = (int)pack2(p0, p1); pw[1] = (int)pack2(p2, p3);
      *(i32x2*)&Pl[w][l15 * 72 + s * 16 + g * 4] = pw;   // P[q][kv] contiguous
    }
    l_part = l_part * alpha + psum;
    m_run = m_new;

    // ---- rescale O (rows q = 4g+r) ----
    float afr[4];
#pragma unroll
    for (int r = 0; r < 4; ++r) afr[r] = __shfl(alpha, g * 4 + r);
#pragma unroll
    for (int n = 0; n < 4; ++n)
#pragma unroll
      for (int r = 0; r < 4; ++r) of[n][r] *= afr[r];

    asm volatile("s_waitcnt lgkmcnt(0)" ::: "memory");  // P writes -> P reads

    // ---- O += P @ V ----
#pragma unroll
    for (int k2 = 0; k2 < 2; ++k2) {
      const bf16x8 pa = *(const bf16x8*)&Pl[w][l15 * 72 + k2 * 32 + g * 8];
#pragma unroll
      for (int n = 0; n < 4; ++n) {
        const bf16x8 vf = *(const bf16x8*)&Vt[(n * 16 + l15) * 72 + k2 * 32 + g * 8];
        of[n] = __builtin_amdgcn_mfma_f32_16x16x32_bf16(pa, vf, of[n], 0, 0, 0);
      }
    }
    __syncthreads();
  }

  // ---- finalize: O / l , write [b][s][h*64+d] bf16 ----
  float lt = l_part;
  lt += __shfl_xor(lt, 16);
  lt += __shfl_xor(lt, 32);
  float inv[4];
#pragma unroll
  for (int r = 0; r < 4; ++r) inv[r] = 1.f / __shfl(lt, g * 4 + r);
#pragma unroll
  for (int n = 0; n < 4; ++n) {
    const int d = h * 64 + n * 16 + l15;
#pragma unroll
    for (int r = 0; r < 4; ++r) {
      const int srow_ = qt * 64 + w * 16 + g * 4 + r;
      o_ws[((size_t)b * SLEN + srow_) * DMODEL + d] = f2bf(of[n][r] * inv[r]);
    }
  }
}

// ---------------------------------------------------------------------------
// Output projection: out = O @ Wo^T + bo (fp32 out). A is already bf16.
// ---------------------------------------------------------------------------
__global__ __launch_bounds__(256)
void gemm_out(const unsigned short* __restrict__ ow,
              const float* __restrict__ Wo, const float* __restrict__ bo,
              float* __restrict__ out)
{
  const int n0 = blockIdx.x * 128;
  const int m0 = blockIdx.y * 128;
  const int tid = threadIdx.x;
  const int lane = tid & 63, wid = tid >> 6;
  const int l15 = lane & 15, g = lane >> 4;
  const int wr = wid >> 1, wc = wid & 1;

  __shared__ __align__(16) unsigned short Al[128 * 40];
  __shared__ __align__(16) unsigned short Bl[128 * 40];

  const int srow = tid >> 1, sh = tid & 1;
  const unsigned short* __restrict__ Ag = ow + (size_t)(m0 + srow) * DMODEL + sh * 16;
  const float* __restrict__ Bg = Wo + (size_t)(n0 + srow) * DMODEL + sh * 16;

  f32x4 acc[4][4];
#pragma unroll
  for (int i = 0; i < 4; ++i)
#pragma unroll
    for (int j = 0; j < 4; ++j) acc[i][j] = zero4();

  i32x4 ar0 = *(const i32x4*)Ag;
  i32x4 ar1 = *(const i32x4*)(Ag + 8);
  f32x4 br[4];
#pragma unroll
  for (int i = 0; i < 4; ++i) br[i] = *(const f32x4*)(Bg + i * 4);

  for (int kk = 0; kk < 32; ++kk) {
    __syncthreads();
    i32x4 wb0, wb1;
    wb0[0] = pack2(br[0][0], br[0][1]); wb0[1] = pack2(br[0][2], br[0][3]);
    wb0[2] = pack2(br[1][0], br[1][1]); wb0[3] = pack2(br[1][2], br[1][3]);
    wb1[0] = pack2(br[2][0], br[2][1]); wb1[1] = pack2(br[2][2], br[2][3]);
    wb1[2] = pack2(br[3][0], br[3][1]); wb1[3] = pack2(br[3][2], br[3][3]);
    *(i32x4*)&Al[srow * 40 + sh * 16]     = ar0;
    *(i32x4*)&Al[srow * 40 + sh * 16 + 8] = ar1;
    *(i32x4*)&Bl[srow * 40 + sh * 16]     = wb0;
    *(i32x4*)&Bl[srow * 40 + sh * 16 + 8] = wb1;
    __syncthreads();
    if (kk < 31) {
      const unsigned short* Ap = Ag + (kk + 1) * 32;
      const float* Bp = Bg + (kk + 1) * 32;
      ar0 = *(const i32x4*)Ap;
      ar1 = *(const i32x4*)(Ap + 8);
#pragma unroll
      for (int i = 0; i < 4; ++i) br[i] = *(const f32x4*)(Bp + i * 4);
    }
    bf16x8 afr[4], bfr[4];
#pragma unroll
    for (int i = 0; i < 4; ++i) {
      afr[i] = *(const bf16x8*)&Al[(wr * 64 + i * 16 + l15) * 40 + g * 8];
      bfr[i] = *(const bf16x8*)&Bl[(wc * 64 + i * 16 + l15) * 40 + g * 8];
    }
#pragma unroll
    for (int mi = 0; mi < 4; ++mi)
#pragma unroll
      for (int ni = 0; ni < 4; ++ni)
        acc[mi][ni] = __builtin_amdgcn_mfma_f32_16x16x32_bf16(
            afr[mi], bfr[ni], acc[mi][ni], 0, 0, 0);
  }

  float bv4[4];
#pragma unroll
  for (int ni = 0; ni < 4; ++ni) bv4[ni] = bo[n0 + wc * 64 + ni * 16 + l15];
#pragma unroll
  for (int mi = 0; mi < 4; ++mi) {
#pragma unroll
    for (int ni = 0; ni < 4; ++ni) {
      const int n = n0 + wc * 64 + ni * 16 + l15;
#pragma unroll
      for (int r = 0; r < 4; ++r) {
        const int m = m0 + wr * 64 + mi * 16 + 4 * g + r;
        out[(size_t)m * DMODEL + n] = acc[mi][ni][r] + bv4[ni];
      }
    }
  }
}

// ---------------------------------------------------------------------------
extern "C" void kernel_launch(void* const* d_in, const int* in_sizes, int n_in,
                              void* d_out, int out_size, void* d_ws, size_t ws_size,
                              hipStream_t stream) {
  const float* query = (const float*)d_in[0];
  const float* key_  = (const float*)d_in[1];
  const float* value = (const float*)d_in[2];
  const int*   mask  = (const int*)d_in[3];
  const float* Wq = (const float*)d_in[4];
  const float* bq = (const float*)d_in[5];
  const float* Wk = (const float*)d_in[6];
  const float* bk = (const float*)d_in[7];
  const float* Wv = (const float*)d_in[8];
  const float* bv = (const float*)d_in[9];
  const float* Wo = (const float*)d_in[10];
  const float* bo = (const float*)d_in[11];
  float* out = (float*)d_out;

  char* ws = (char*)d_ws;
  unsigned short* q_ws = (unsigned short*)(ws);
  unsigned short* k_ws = (unsigned short*)(ws + (size_t)16777216);
  unsigned short* v_ws = (unsigned short*)(ws + (size_t)2 * 16777216);
  unsigned short* o_ws = (unsigned short*)(ws + (size_t)3 * 16777216);

  gemm_qkv<<<dim3(8, 64, 3), 256, 0, stream>>>(query, key_, value,
                                               Wq, bq, Wk, bk, Wv, bv,
                                               q_ws, k_ws, v_ws);
  attn<<<dim3(64, 32), 256, 0, stream>>>(q_ws, k_ws, v_ws, mask, o_ws);
  gemm_out<<<dim3(8, 64), 256, 0, stream>>>(o_ws, Wo, bo, out);
}

// Round 2
// 292.010 us; speedup vs baseline: 1.1516x; 1.1516x over previous
//
#include <hip/hip_runtime.h>

// MultiHeadedAttention: B=4, S=2048, H=16, D_K=64, D_MODEL=1024
// Pipeline: [gemm_qkv z=0..2] -> [flash attn] -> [gemm_out]
// ws layout (64MB):
//   q_ws [64][2048][64] bf16 @ 0      (16 MB)  (pre-scaled by 0.125*log2e)
//   k_ws [64][2048][64] bf16 @ 16MB   (16 MB)
//   vT   [64][64][2048] bf16 @ 32MB   (16 MB)  (V transposed per head: [bh][d][s])
//   o_ws [4][2048][1024] bf16 @ 48MB  (16 MB)

#define DMODEL 1024
#define SLEN 2048
#define NHEAD 16
#define LOG2E 1.44269504088896340736f

typedef __attribute__((ext_vector_type(4))) float f32x4;
typedef __attribute__((ext_vector_type(8))) short bf16x8;
typedef __attribute__((ext_vector_type(4))) int i32x4;
typedef __attribute__((ext_vector_type(2))) int i32x2;

__device__ __forceinline__ unsigned short f2bf(float f) {
  __bf16 h = (__bf16)f;
  union { __bf16 h; unsigned short u; } cv; cv.h = h; return cv.u;
}
__device__ __forceinline__ unsigned pk(float a, float b) {
  return (unsigned)f2bf(a) | ((unsigned)f2bf(b) << 16);
}
__device__ __forceinline__ float fexp2(float x) {
#if __has_builtin(__builtin_amdgcn_exp2f)
  return __builtin_amdgcn_exp2f(x);
#else
  return exp2f(x);
#endif
}
__device__ __forceinline__ f32x4 zero4() {
  f32x4 z; z[0] = 0.f; z[1] = 0.f; z[2] = 0.f; z[3] = 0.f; return z;
}
// async global->LDS, 16B per lane; lds dest wave-uniform base + lane*16
__device__ __forceinline__ void gload16(const void* g, void* l) {
  __builtin_amdgcn_global_load_lds(
      (const __attribute__((address_space(1))) unsigned int*)(uintptr_t)g,
      (__attribute__((address_space(3))) unsigned int*)(uintptr_t)l, 16, 0, 0);
}

// ---------------------------------------------------------------------------
// QKV projection: Y = X @ W^T + b ; M=8192,N=1024,K=1024 ; out bf16 per-head.
// z==2 (V): epilogue transposes tile via LDS and stores V^T [bh][d][s].
// ---------------------------------------------------------------------------
__global__ __launch_bounds__(256)
void gemm_qkv(const float* __restrict__ xq, const float* __restrict__ xk,
              const float* __restrict__ xv,
              const float* __restrict__ Wq, const float* __restrict__ bq,
              const float* __restrict__ Wk, const float* __restrict__ bk,
              const float* __restrict__ Wv, const float* __restrict__ bv,
              unsigned short* __restrict__ qw, unsigned short* __restrict__ kw,
              unsigned short* __restrict__ vw)
{
  const int z = blockIdx.z;
  const float* __restrict__ X    = (z == 0) ? xq : (z == 1) ? xk : xv;
  const float* __restrict__ W    = (z == 0) ? Wq : (z == 1) ? Wk : Wv;
  const float* __restrict__ bias = (z == 0) ? bq : (z == 1) ? bk : bv;
  const float scale = (z == 0) ? 0.125f * LOG2E : 1.0f;

  const int n0 = blockIdx.x * 128;
  const int m0 = blockIdx.y * 128;
  const int tid = threadIdx.x;
  const int lane = tid & 63, wid = tid >> 6;
  const int l15 = lane & 15, g = lane >> 4;
  const int wr = wid >> 1, wc = wid & 1;

  __shared__ __align__(16) unsigned short SM[2 * 128 * 40];   // Al | Bl ; reused as TT
  unsigned short* Al = SM;
  unsigned short* Bl = SM + 128 * 40;
  unsigned short* TT = SM;                                    // [64][136] epilogue

  const int srow = tid >> 1, sh = tid & 1;   // 2 threads/row, 16 floats each
  const float* __restrict__ Ag = X + (size_t)(m0 + srow) * DMODEL + sh * 16;
  const float* __restrict__ Bg = W + (size_t)(n0 + srow) * DMODEL + sh * 16;

  f32x4 acc[4][4];
#pragma unroll
  for (int i = 0; i < 4; ++i)
#pragma unroll
    for (int j = 0; j < 4; ++j) acc[i][j] = zero4();

  f32x4 ar[4], br[4];
#pragma unroll
  for (int i = 0; i < 4; ++i) {
    ar[i] = *(const f32x4*)(Ag + i * 4);
    br[i] = *(const f32x4*)(Bg + i * 4);
  }

  for (int kk = 0; kk < 32; ++kk) {
    __syncthreads();
    i32x4 wa0, wa1, wb0, wb1;
    wa0[0] = pk(ar[0][0], ar[0][1]); wa0[1] = pk(ar[0][2], ar[0][3]);
    wa0[2] = pk(ar[1][0], ar[1][1]); wa0[3] = pk(ar[1][2], ar[1][3]);
    wa1[0] = pk(ar[2][0], ar[2][1]); wa1[1] = pk(ar[2][2], ar[2][3]);
    wa1[2] = pk(ar[3][0], ar[3][1]); wa1[3] = pk(ar[3][2], ar[3][3]);
    wb0[0] = pk(br[0][0], br[0][1]); wb0[1] = pk(br[0][2], br[0][3]);
    wb0[2] = pk(br[1][0], br[1][1]); wb0[3] = pk(br[1][2], br[1][3]);
    wb1[0] = pk(br[2][0], br[2][1]); wb1[1] = pk(br[2][2], br[2][3]);
    wb1[2] = pk(br[3][0], br[3][1]); wb1[3] = pk(br[3][2], br[3][3]);
    *(i32x4*)&Al[srow * 40 + sh * 16]     = wa0;
    *(i32x4*)&Al[srow * 40 + sh * 16 + 8] = wa1;
    *(i32x4*)&Bl[srow * 40 + sh * 16]     = wb0;
    *(i32x4*)&Bl[srow * 40 + sh * 16 + 8] = wb1;
    __syncthreads();
    if (kk < 31) {
      const float* Ap = Ag + (kk + 1) * 32;
      const float* Bp = Bg + (kk + 1) * 32;
#pragma unroll
      for (int i = 0; i < 4; ++i) {
        ar[i] = *(const f32x4*)(Ap + i * 4);
        br[i] = *(const f32x4*)(Bp + i * 4);
      }
    }
    bf16x8 afr[4], bfr[4];
#pragma unroll
    for (int i = 0; i < 4; ++i) {
      afr[i] = *(const bf16x8*)&Al[(wr * 64 + i * 16 + l15) * 40 + g * 8];
      bfr[i] = *(const bf16x8*)&Bl[(wc * 64 + i * 16 + l15) * 40 + g * 8];
    }
#pragma unroll
    for (int mi = 0; mi < 4; ++mi)
#pragma unroll
      for (int ni = 0; ni < 4; ++ni)
        acc[mi][ni] = __builtin_amdgcn_mfma_f32_16x16x32_bf16(
            afr[mi], bfr[ni], acc[mi][ni], 0, 0, 0);
  }

  float bv4[4];
#pragma unroll
  for (int ni = 0; ni < 4; ++ni) bv4[ni] = bias[n0 + wc * 64 + ni * 16 + l15];

  if (z == 2) {
    // ---- transpose epilogue: store V^T [b*1024 + n][s] ----
    const int bb = m0 >> 11, s0 = m0 & 2047;
#pragma unroll
    for (int p = 0; p < 2; ++p) {
      __syncthreads();
      if (wc == p) {
#pragma unroll
        for (int mi = 0; mi < 4; ++mi)
#pragma unroll
          for (int ni = 0; ni < 4; ++ni)
#pragma unroll
            for (int r = 0; r < 4; ++r)
              TT[(ni * 16 + l15) * 136 + wr * 64 + mi * 16 + 4 * g + r] =
                  f2bf(acc[mi][ni][r] + bv4[ni]);
      }
      __syncthreads();
      const int rr = tid >> 2, cc = (tid & 3) * 32;
      unsigned short* dp = vw + ((size_t)(bb * 1024 + n0 + p * 64 + rr)) * 2048 + s0 + cc;
      const unsigned short* sp = &TT[rr * 136 + cc];
#pragma unroll
      for (int j = 0; j < 4; ++j)
        *(i32x4*)(void*)(dp + j * 8) = *(const i32x4*)(const void*)(sp + j * 8);
    }
    return;
  }

  unsigned short* __restrict__ dst = (z == 0) ? qw : kw;
#pragma unroll
  for (int mi = 0; mi < 4; ++mi) {
#pragma unroll
    for (int ni = 0; ni < 4; ++ni) {
      const int n = n0 + wc * 64 + ni * 16 + l15;
      const int h = n >> 6, d = n & 63;
#pragma unroll
      for (int r = 0; r < 4; ++r) {
        const int m = m0 + wr * 64 + mi * 16 + 4 * g + r;
        const int b = m >> 11, s = m & 2047;
        const float val = (acc[mi][ni][r] + bv4[ni]) * scale;
        dst[((size_t)(b * NHEAD + h) * SLEN + s) * 64 + d] = f2bf(val);
      }
    }
  }
}

// ---------------------------------------------------------------------------
// Flash attention. 4 waves x 32 q-rows (QBLK 128). KVBLK 64, double-buffered
// global_load_lds staging with XOR-swizzled source; exp2-domain online softmax
// with defer-max; mask folded into MFMA C-init.
// ---------------------------------------------------------------------------
__global__ __launch_bounds__(256, 3)
void attn(const unsigned short* __restrict__ q_ws,
          const unsigned short* __restrict__ k_ws,
          const unsigned short* __restrict__ vT,
          const int* __restrict__ mask,
          unsigned short* __restrict__ o_ws)
{
  const int bh = blockIdx.x;            // 0..63
  const int qt = blockIdx.y;            // 0..15
  const int b = bh >> 4, h = bh & 15;
  const int tid = threadIdx.x, w = tid >> 6, lane = tid & 63;
  const int l15 = lane & 15, g = lane >> 4;

  __shared__ __align__(16) unsigned short Kb[2][64 * 64];   // [kv][d] linear, swz source
  __shared__ __align__(16) unsigned short Vb[2][64 * 64];   // [d][kv] linear, swz source
  __shared__ __align__(16) unsigned short Pl[4][16 * 64];   // per-wave [q][kv] XOR-swz
  __shared__ __align__(16) float maskf[2048];

  // ---- stage mask bias (0 / -1e9) once ----
  {
    const int4* mp = (const int4*)(mask + b * SLEN);
    const int4 ma = mp[tid * 2], mb = mp[tid * 2 + 1];
    float4 f0, f1;
    f0.x = ma.x ? 0.f : -1e9f; f0.y = ma.y ? 0.f : -1e9f;
    f0.z = ma.z ? 0.f : -1e9f; f0.w = ma.w ? 0.f : -1e9f;
    f1.x = mb.x ? 0.f : -1e9f; f1.y = mb.y ? 0.f : -1e9f;
    f1.z = mb.z ? 0.f : -1e9f; f1.w = mb.w ? 0.f : -1e9f;
    *(float4*)&maskf[tid * 8]     = f0;
    *(float4*)&maskf[tid * 8 + 4] = f1;
  }

  const size_t head = (size_t)bh * SLEN;
  const int r8 = lane >> 3, c8 = lane & 7;
  const int swz = ((c8 ^ r8) * 16);              // source chunk pre-swizzle (bytes)
  const unsigned pswz = (unsigned)((l15 & 7) << 4);

  // ---- Q fragments (2 q-subtiles of 16 rows per wave) ----
  const int qbase = qt * 128 + w * 32;
  bf16x8 qf[2][2];
  {
    const unsigned short* qp0 = q_ws + (head + qbase + l15) * 64;
    const unsigned short* qp1 = q_ws + (head + qbase + 16 + l15) * 64;
    qf[0][0] = *(const bf16x8*)(qp0 + g * 8);
    qf[0][1] = *(const bf16x8*)(qp0 + 32 + g * 8);
    qf[1][0] = *(const bf16x8*)(qp1 + g * 8);
    qf[1][1] = *(const bf16x8*)(qp1 + 32 + g * 8);
  }

  // ---- async stage of K and V^T tiles (wave w covers rows w*16..w*16+15) ----
  auto stage = [&](int kt2, int bufi) {
#pragma unroll
    for (int cl = 0; cl < 2; ++cl) {
      const int r = w * 16 + cl * 8 + r8;                      // tile row (kv or d)
      const char* gk = (const char*)(k_ws + (head + kt2 * 64 + r) * 64) + swz;
      gload16(gk, &Kb[bufi][(w * 16 + cl * 8) * 64]);
      const char* gv = (const char*)(vT + ((size_t)(bh * 64 + r)) * SLEN + kt2 * 64) + swz;
      gload16(gv, &Vb[bufi][(w * 16 + cl * 8) * 64]);
    }
  };

  stage(0, 0);
  __syncthreads();

  float m_run[2] = {-1e30f, -1e30f};
  float l_run[2] = {0.f, 0.f};
  f32x4 of[2][4];
#pragma unroll
  for (int qi = 0; qi < 2; ++qi)
#pragma unroll
    for (int n = 0; n < 4; ++n) of[qi][n] = zero4();

  unsigned short* Pw = (unsigned short*)Pl[w];
  int cur = 0;

  for (int kt = 0; kt < 32; ++kt) {
    if (kt + 1 < 32) stage(kt + 1, cur ^ 1);
    const char* Kc = (const char*)Kb[cur];
    const char* Vc = (const char*)Vb[cur];
    const int kv0 = kt * 64;

    f32x4 mv[4];
#pragma unroll
    for (int s = 0; s < 4; ++s) mv[s] = *(const f32x4*)&maskf[kv0 + s * 16 + g * 4];

#pragma unroll
    for (int qi = 0; qi < 2; ++qi) {
      // ---- S^T = K @ Q^T with mask as C-init ----
      f32x4 sac[4];
#pragma unroll
      for (int s = 0; s < 4; ++s) {
        const char* kr = Kc + (s * 16 + l15) * 128;
        const bf16x8 kf0 = *(const bf16x8*)(kr + ((unsigned)(g * 16) ^ pswz));
        const bf16x8 kf1 = *(const bf16x8*)(kr + ((unsigned)(64 + g * 16) ^ pswz));
        f32x4 zt = mv[s];
        zt = __builtin_amdgcn_mfma_f32_16x16x32_bf16(kf0, qf[qi][0], zt, 0, 0, 0);
        sac[s] = __builtin_amdgcn_mfma_f32_16x16x32_bf16(kf1, qf[qi][1], zt, 0, 0, 0);
      }

      // ---- online softmax (exp2 domain), defer-max THR=8 ----
      float tmax = -3.0e38f;
#pragma unroll
      for (int s = 0; s < 4; ++s)
#pragma unroll
        for (int r = 0; r < 4; ++r) tmax = fmaxf(tmax, sac[s][r]);
      tmax = fmaxf(tmax, __shfl_xor(tmax, 16));
      tmax = fmaxf(tmax, __shfl_xor(tmax, 32));
      if (!__all(tmax <= m_run[qi] + 8.f)) {
        const float mnew = fmaxf(m_run[qi], tmax);
        const float alpha = fexp2(m_run[qi] - mnew);
        float af[4];
#pragma unroll
        for (int r = 0; r < 4; ++r) af[r] = __shfl(alpha, g * 4 + r);
#pragma unroll
        for (int n = 0; n < 4; ++n)
#pragma unroll
          for (int r = 0; r < 4; ++r) of[qi][n][r] *= af[r];
        l_run[qi] *= alpha;
        m_run[qi] = mnew;
      }
      float psum = 0.f;
      unsigned pr[4][2];
#pragma unroll
      for (int s = 0; s < 4; ++s) {
        const float p0 = fexp2(sac[s][0] - m_run[qi]);
        const float p1 = fexp2(sac[s][1] - m_run[qi]);
        const float p2 = fexp2(sac[s][2] - m_run[qi]);
        const float p3 = fexp2(sac[s][3] - m_run[qi]);
        psum += (p0 + p1) + (p2 + p3);
        pr[s][0] = pk(p0, p1); pr[s][1] = pk(p2, p3);
      }
      l_run[qi] += psum;
#pragma unroll
      for (int s = 0; s < 4; ++s) {
        i32x2 wv; wv[0] = (int)pr[s][0]; wv[1] = (int)pr[s][1];
        *(i32x2*)(void*)((char*)Pw + l15 * 128 + ((unsigned)(s * 32 + g * 8) ^ pswz)) = wv;
      }

      // ---- O += P @ V ----
#pragma unroll
      for (int k2 = 0; k2 < 2; ++k2) {
        const bf16x8 pa = *(const bf16x8*)(const void*)(
            (const char*)Pw + l15 * 128 + ((unsigned)(k2 * 64 + g * 16) ^ pswz));
#pragma unroll
        for (int n = 0; n < 4; ++n) {
          const bf16x8 vf = *(const bf16x8*)(
              Vc + (n * 16 + l15) * 128 + ((unsigned)(k2 * 64 + g * 16) ^ pswz));
          of[qi][n] = __builtin_amdgcn_mfma_f32_16x16x32_bf16(pa, vf, of[qi][n], 0, 0, 0);
        }
      }
    }
    __syncthreads();
    cur ^= 1;
  }

  // ---- finalize ----
#pragma unroll
  for (int qi = 0; qi < 2; ++qi) {
    float lt = l_run[qi];
    lt += __shfl_xor(lt, 16);
    lt += __shfl_xor(lt, 32);
    float inv[4];
#pragma unroll
    for (int r = 0; r < 4; ++r) inv[r] = 1.f / __shfl(lt, g * 4 + r);
    const int qrow0 = qt * 128 + w * 32 + qi * 16;
#pragma unroll
    for (int n = 0; n < 4; ++n) {
      const int d = h * 64 + n * 16 + l15;
#pragma unroll
      for (int r = 0; r < 4; ++r) {
        const int sr = qrow0 + 4 * g + r;
        o_ws[((size_t)b * SLEN + sr) * DMODEL + d] = f2bf(of[qi][n][r] * inv[r]);
      }
    }
  }
}

// ---------------------------------------------------------------------------
// Output projection: out = O @ Wo^T + bo (fp32 out). A is already bf16.
// ---------------------------------------------------------------------------
__global__ __launch_bounds__(256)
void gemm_out(const unsigned short* __restrict__ ow,
              const float* __restrict__ Wo, const float* __restrict__ bo,
              float* __restrict__ out)
{
  const int n0 = blockIdx.x * 128;
  const int m0 = blockIdx.y * 128;
  const int tid = threadIdx.x;
  const int lane = tid & 63, wid = tid >> 6;
  const int l15 = lane & 15, g = lane >> 4;
  const int wr = wid >> 1, wc = wid & 1;

  __shared__ __align__(16) unsigned short Al[128 * 40];
  __shared__ __align__(16) unsigned short Bl[128 * 40];

  const int srow = tid >> 1, sh = tid & 1;
  const unsigned short* __restrict__ Ag = ow + (size_t)(m0 + srow) * DMODEL + sh * 16;
  const float* __restrict__ Bg = Wo + (size_t)(n0 + srow) * DMODEL + sh * 16;

  f32x4 acc[4][4];
#pragma unroll
  for (int i = 0; i < 4; ++i)
#pragma unroll
    for (int j = 0; j < 4; ++j) acc[i][j] = zero4();

  i32x4 ar0 = *(const i32x4*)Ag;
  i32x4 ar1 = *(const i32x4*)(Ag + 8);
  f32x4 br[4];
#pragma unroll
  for (int i = 0; i < 4; ++i) br[i] = *(const f32x4*)(Bg + i * 4);

  for (int kk = 0; kk < 32; ++kk) {
    __syncthreads();
    i32x4 wb0, wb1;
    wb0[0] = pk(br[0][0], br[0][1]); wb0[1] = pk(br[0][2], br[0][3]);
    wb0[2] = pk(br[1][0], br[1][1]); wb0[3] = pk(br[1][2], br[1][3]);
    wb1[0] = pk(br[2][0], br[2][1]); wb1[1] = pk(br[2][2], br[2][3]);
    wb1[2] = pk(br[3][0], br[3][1]); wb1[3] = pk(br[3][2], br[3][3]);
    *(i32x4*)&Al[srow * 40 + sh * 16]     = ar0;
    *(i32x4*)&Al[srow * 40 + sh * 16 + 8] = ar1;
    *(i32x4*)&Bl[srow * 40 + sh * 16]     = wb0;
    *(i32x4*)&Bl[srow * 40 + sh * 16 + 8] = wb1;
    __syncthreads();
    if (kk < 31) {
      const unsigned short* Ap = Ag + (kk + 1) * 32;
      const float* Bp = Bg + (kk + 1) * 32;
      ar0 = *(const i32x4*)Ap;
      ar1 = *(const i32x4*)(Ap + 8);
#pragma unroll
      for (int i = 0; i < 4; ++i) br[i] = *(const f32x4*)(Bp + i * 4);
    }
    bf16x8 afr[4], bfr[4];
#pragma unroll
    for (int i = 0; i < 4; ++i) {
      afr[i] = *(const bf16x8*)&Al[(wr * 64 + i * 16 + l15) * 40 + g * 8];
      bfr[i] = *(const bf16x8*)&Bl[(wc * 64 + i * 16 + l15) * 40 + g * 8];
    }
#pragma unroll
    for (int mi = 0; mi < 4; ++mi)
#pragma unroll
      for (int ni = 0; ni < 4; ++ni)
        acc[mi][ni] = __builtin_amdgcn_mfma_f32_16x16x32_bf16(
            afr[mi], bfr[ni], acc[mi][ni], 0, 0, 0);
  }

  float bv4[4];
#pragma unroll
  for (int ni = 0; ni < 4; ++ni) bv4[ni] = bo[n0 + wc * 64 + ni * 16 + l15];
#pragma unroll
  for (int mi = 0; mi < 4; ++mi) {
#pragma unroll
    for (int ni = 0; ni < 4; ++ni) {
      const int n = n0 + wc * 64 + ni * 16 + l15;
#pragma unroll
      for (int r = 0; r < 4; ++r) {
        const int m = m0 + wr * 64 + mi * 16 + 4 * g + r;
        out[(size_t)m * DMODEL + n] = acc[mi][ni][r] + bv4[ni];
      }
    }
  }
}

// ---------------------------------------------------------------------------
extern "C" void kernel_launch(void* const* d_in, const int* in_sizes, int n_in,
                              void* d_out, int out_size, void* d_ws, size_t ws_size,
                              hipStream_t stream) {
  const float* query = (const float*)d_in[0];
  const float* key_  = (const float*)d_in[1];
  const float* value = (const float*)d_in[2];
  const int*   mask  = (const int*)d_in[3];
  const float* Wq = (const float*)d_in[4];
  const float* bq = (const float*)d_in[5];
  const float* Wk = (const float*)d_in[6];
  const float* bk = (const float*)d_in[7];
  const float* Wv = (const float*)d_in[8];
  const float* bv = (const float*)d_in[9];
  const float* Wo = (const float*)d_in[10];
  const float* bo = (const float*)d_in[11];
  float* out = (float*)d_out;

  char* ws = (char*)d_ws;
  unsigned short* q_ws = (unsigned short*)(ws);
  unsigned short* k_ws = (unsigned short*)(ws + (size_t)16777216);
  unsigned short* vT   = (unsigned short*)(ws + (size_t)2 * 16777216);
  unsigned short* o_ws = (unsigned short*)(ws + (size_t)3 * 16777216);

  gemm_qkv<<<dim3(8, 64, 3), 256, 0, stream>>>(query, key_, value,
                                               Wq, bq, Wk, bk, Wv, bv,
                                               q_ws, k_ws, vT);
  attn<<<dim3(64, 16), 256, 0, stream>>>(q_ws, k_ws, vT, mask, o_ws);
  gemm_out<<<dim3(8, 64), 256, 0, stream>>>(o_ws, Wo, bo, out);
}